// Round 1
// baseline (677.933 us; speedup 1.0000x reference)
//
#include <hip/hip_runtime.h>
#include <hip/hip_bf16.h>

#define Bsz 2048
#define Tn  200
#define Fn  64
#define Hn  128
#define INn 256   // 2F + H
#define Gn  384   // 3H
#define BBn 8     // batch rows per block

typedef __bf16 bf16x8 __attribute__((ext_vector_type(8)));
typedef float  f32x4  __attribute__((ext_vector_type(4)));

__device__ __forceinline__ float sigm(float x)  { return 1.f / (1.f + __expf(-x)); }
__device__ __forceinline__ float tanh_(float x) { return 1.f - 2.f / (__expf(2.f * x) + 1.f); }

// One block owns BBn=8 batch rows and scans all Tn timesteps.
// 8 waves; wave w holds bf16 B-fragments for gate-cols [48w,48w+48) of w_ih
// (K=256) and w_hh (K=128), plus cols [16w,16w+16) of Wdh (K=64).
// MFMA 16x16x32_bf16; A rows 8..15 are zero-padded.
__global__ __launch_bounds__(512, 2) void grud_scan(
    const float* __restrict__ values, const float* __restrict__ masks,
    const float* __restrict__ deltas, const float* __restrict__ x_locf,
    const float* __restrict__ emp_mean,
    const float* __restrict__ Wdh, const float* __restrict__ bdh,
    const float* __restrict__ Wdx, const float* __restrict__ bdx,
    const float* __restrict__ w_ih, const float* __restrict__ w_hh,
    const float* __restrict__ b_ih, const float* __restrict__ b_hh,
    const float* __restrict__ Wc, const float* __restrict__ bc,
    float* __restrict__ out)
{
    __shared__ __align__(16) __bf16 in_bf[16][INn + 8];  // [x_rep | h | m], rows 8..15 zero
    __shared__ __align__(16) __bf16 d_bf[16][Fn + 8];
    __shared__ float h_lds[BBn][Hn];
    __shared__ float gi_lds[BBn][Gn + 1];
    __shared__ float gh_lds[BBn][Gn + 1];
    __shared__ float bih_s[Gn], bhh_s[Gn], bdh_s[Hn];
    __shared__ float wdxd_s[Fn], bdx_s[Fn], emp_s[Fn];

    const int tid  = threadIdx.x;
    const int w    = tid >> 6;     // wave id 0..7
    const int lane = tid & 63;
    const int ncol = lane & 15;    // MFMA n / A-row index
    const int kg   = lane >> 4;    // k-chunk group 0..3
    const int b0   = blockIdx.x * BBn;

    // ---- init LDS ----
    for (int i = tid; i < 16 * (INn + 8); i += 512) ((__bf16*)in_bf)[i] = (__bf16)0.f;
    for (int i = tid; i < 16 * (Fn + 8);  i += 512) ((__bf16*)d_bf)[i]  = (__bf16)0.f;
    for (int i = tid; i < BBn * Hn;       i += 512) ((float*)h_lds)[i]  = 0.f;
    for (int i = tid; i < Gn; i += 512) { bih_s[i] = b_ih[i]; bhh_s[i] = b_hh[i]; }
    for (int i = tid; i < Hn; i += 512) bdh_s[i] = bdh[i];
    for (int i = tid; i < Fn; i += 512) {
        wdxd_s[i] = Wdx[i * Fn + i];   // diag(Wdx)
        bdx_s[i]  = bdx[i];
        emp_s[i]  = emp_mean[i];
    }

    // ---- load weight B-fragments (bf16, register-resident) ----
    // B[k][n] layout: lane holds k = kc*32 + kg*8 + e, n = base + ncol; W[n][k] row-major
    bf16x8 wih[3][8], whh[3][4], wdhf[2];
    #pragma unroll
    for (int nt = 0; nt < 3; ++nt) {
        const int c = w * 48 + nt * 16 + ncol;
        #pragma unroll
        for (int kc = 0; kc < 8; ++kc) {
            const float* p = w_ih + (size_t)c * INn + kc * 32 + kg * 8;
            bf16x8 v;
            #pragma unroll
            for (int e = 0; e < 8; ++e) v[e] = (__bf16)p[e];
            wih[nt][kc] = v;
        }
        #pragma unroll
        for (int kc = 0; kc < 4; ++kc) {
            const float* p = w_hh + (size_t)c * Hn + kc * 32 + kg * 8;
            bf16x8 v;
            #pragma unroll
            for (int e = 0; e < 8; ++e) v[e] = (__bf16)p[e];
            whh[nt][kc] = v;
        }
    }
    {
        const int c = w * 16 + ncol;
        #pragma unroll
        for (int kc = 0; kc < 2; ++kc) {
            const float* p = Wdh + (size_t)c * Fn + kc * 32 + kg * 8;
            bf16x8 v;
            #pragma unroll
            for (int e = 0; e < 8; ++e) v[e] = (__bf16)p[e];
            wdhf[kc] = v;
        }
    }

    __syncthreads();

    // thread (r_ld, f_ld) owns one (row, feature) element for input streaming
    const int r_ld = w;
    const int f_ld = lane;
    size_t base0 = ((size_t)(b0 + r_ld) * Tn + 0) * Fn + f_ld;
    float x_c = values[base0], m_c = masks[base0], d_c = deltas[base0], xl_c = x_locf[base0];

    const f32x4 fz = {0.f, 0.f, 0.f, 0.f};

    for (int t = 0; t < Tn; ++t) {
        // ---- P1: elementwise input prep (uses prefetched regs) ----
        {
            float gx = __expf(-fmaxf(d_c * wdxd_s[f_ld] + bdx_s[f_ld], 0.f));
            float xh = gx * xl_c + (1.f - gx) * emp_s[f_ld];
            float xr = m_c * x_c + (1.f - m_c) * xh;
            in_bf[r_ld][f_ld]           = (__bf16)xr;
            in_bf[r_ld][Fn + Hn + f_ld] = (__bf16)m_c;  // m at cols 192..256
            d_bf[r_ld][f_ld]            = (__bf16)d_c;
        }
        // prefetch t+1 into registers (hides HBM latency under P2/P3/P4)
        {
            int tn = (t + 1 < Tn) ? t + 1 : Tn - 1;
            size_t base = ((size_t)(b0 + r_ld) * Tn + tn) * Fn + f_ld;
            x_c = values[base]; m_c = masks[base]; d_c = deltas[base]; xl_c = x_locf[base];
        }
        __syncthreads();

        // ---- P2: gamma_h MFMA + h decay; also publish h (bf16) into in_bf ----
        {
            bf16x8 a0 = *(const bf16x8*)&d_bf[ncol][kg * 8];
            bf16x8 a1 = *(const bf16x8*)&d_bf[ncol][32 + kg * 8];
            f32x4 acc = fz;
            acc = __builtin_amdgcn_mfma_f32_16x16x32_bf16(a0, wdhf[0], acc, 0, 0, 0);
            acc = __builtin_amdgcn_mfma_f32_16x16x32_bf16(a1, wdhf[1], acc, 0, 0, 0);
            const int col = w * 16 + ncol;
            #pragma unroll
            for (int i = 0; i < 4; ++i) {
                int row = kg * 4 + i;            // D: row=(lane>>4)*4+i, col=lane&15
                if (row < BBn) {
                    float g  = __expf(-fmaxf(acc[i] + bdh_s[col], 0.f));
                    float hv = h_lds[row][col] * g;
                    h_lds[row][col]      = hv;
                    in_bf[row][Fn + col] = (__bf16)hv;   // h at cols 64..192
                }
            }
        }
        __syncthreads();

        // ---- P3: gi = [x_rep|h|m] @ w_ih^T ; gh = h @ w_hh^T ----
        {
            bf16x8 af[8];
            #pragma unroll
            for (int kc = 0; kc < 8; ++kc)   // A: row=lane&15, k=kc*32+kg*8..+8
                af[kc] = *(const bf16x8*)&in_bf[ncol][kc * 32 + kg * 8];
            f32x4 gacc[3], hacc[3];
            #pragma unroll
            for (int nt = 0; nt < 3; ++nt) { gacc[nt] = fz; hacc[nt] = fz; }
            #pragma unroll
            for (int kc = 0; kc < 8; ++kc)
                #pragma unroll
                for (int nt = 0; nt < 3; ++nt)
                    gacc[nt] = __builtin_amdgcn_mfma_f32_16x16x32_bf16(af[kc], wih[nt][kc], gacc[nt], 0, 0, 0);
            #pragma unroll
            for (int kc = 0; kc < 4; ++kc)   // h occupies k 64..192 -> af[2..5]
                #pragma unroll
                for (int nt = 0; nt < 3; ++nt)
                    hacc[nt] = __builtin_amdgcn_mfma_f32_16x16x32_bf16(af[kc + 2], whh[nt][kc], hacc[nt], 0, 0, 0);
            #pragma unroll
            for (int nt = 0; nt < 3; ++nt)
                #pragma unroll
                for (int i = 0; i < 4; ++i) {
                    int row = kg * 4 + i;
                    if (row < BBn) {
                        int c = w * 48 + nt * 16 + ncol;
                        gi_lds[row][c] = gacc[nt][i];
                        gh_lds[row][c] = hacc[nt][i];
                    }
                }
        }
        __syncthreads();

        // ---- P4: gates + h update ----
        #pragma unroll
        for (int it = 0; it < 2; ++it) {
            int idx = tid + it * 512;          // 8 rows x 128 cols = 1024
            int r = idx >> 7, j = idx & 127;
            float rg = sigm(gi_lds[r][j] + bih_s[j] + gh_lds[r][j] + bhh_s[j]);
            float zg = sigm(gi_lds[r][Hn + j] + bih_s[Hn + j] + gh_lds[r][Hn + j] + bhh_s[Hn + j]);
            float hn = gh_lds[r][2 * Hn + j] + bhh_s[2 * Hn + j];
            float ng = tanh_(gi_lds[r][2 * Hn + j] + bih_s[2 * Hn + j] + rg * hn);
            float ho = h_lds[r][j];
            h_lds[r][j] = (1.f - zg) * ng + zg * ho;
        }
        __syncthreads();
    }

    // ---- epilogue: logits = h @ Wc^T + bc ; sigmoid ----
    if (tid < BBn) {
        float acc = bc[0];
        #pragma unroll 8
        for (int j = 0; j < Hn; ++j) acc += h_lds[tid][j] * Wc[j];
        out[b0 + tid] = sigm(acc);
    }
}

extern "C" void kernel_launch(void* const* d_in, const int* in_sizes, int n_in,
                              void* d_out, int out_size, void* d_ws, size_t ws_size,
                              hipStream_t stream)
{
    (void)in_sizes; (void)n_in; (void)out_size; (void)d_ws; (void)ws_size;
    grud_scan<<<dim3(Bsz / BBn), dim3(512), 0, stream>>>(
        (const float*)d_in[0],  (const float*)d_in[1],  (const float*)d_in[2],
        (const float*)d_in[3],  (const float*)d_in[4],  (const float*)d_in[5],
        (const float*)d_in[6],  (const float*)d_in[7],  (const float*)d_in[8],
        (const float*)d_in[9],  (const float*)d_in[10], (const float*)d_in[11],
        (const float*)d_in[12], (const float*)d_in[13], (const float*)d_in[14],
        (float*)d_out);
}

// Round 2
// 621.524 us; speedup vs baseline: 1.0908x; 1.0908x over previous
//
#include <hip/hip_runtime.h>
#include <hip/hip_bf16.h>

#define Bsz 2048
#define Tn  200
#define Fn  64
#define Hn  128
#define INn 256   // 2F + H
#define BBn 8     // batch rows per block

typedef __bf16 bf16x8 __attribute__((ext_vector_type(8)));
typedef float  f32x4  __attribute__((ext_vector_type(4)));

__device__ __forceinline__ float sigm(float x)  { return 1.f / (1.f + __expf(-x)); }
__device__ __forceinline__ float tanh_(float x) { return 1.f - 2.f / (__expf(2.f * x) + 1.f); }

// One block = 8 batch rows, 8 waves, scans all Tn steps.
// Wave w owns gate columns {nt*128 + 16w + ncol : nt=0,1,2} of w_ih/w_hh and
// gamma/h columns [16w, 16w+16). With MFMA D-layout col=lane&15,
// row=(lane>>4)*4+i, the r/z/n accumulators for one h element land in the
// SAME lane -> gates + h-update fuse into registers (no gi/gh LDS, no 4th
// barrier). h is register-resident fp32. d_bf is double-buffered and written
// one step ahead so gamma_h's MFMA doesn't depend on same-step input prep.
// 2 barriers per step.
__global__ __launch_bounds__(512, 2) void grud_scan(
    const float* __restrict__ values, const float* __restrict__ masks,
    const float* __restrict__ deltas, const float* __restrict__ x_locf,
    const float* __restrict__ emp_mean,
    const float* __restrict__ Wdh, const float* __restrict__ bdh,
    const float* __restrict__ Wdx, const float* __restrict__ bdx,
    const float* __restrict__ w_ih, const float* __restrict__ w_hh,
    const float* __restrict__ b_ih, const float* __restrict__ b_hh,
    const float* __restrict__ Wc, const float* __restrict__ bc,
    float* __restrict__ out)
{
    // stride 264 bf16 = 132 words -> rows 4 banks apart: A-frag b128 reads 2-way (free)
    __shared__ __align__(16) __bf16 in_bf[16][264];   // [x_rep | h | m], rows 8..15 zero
    __shared__ __align__(16) __bf16 d_bf[2][16][72];  // double-buffered deltas
    __shared__ float h_fin[BBn][Hn];                  // epilogue only

    const int tid  = threadIdx.x;
    const int w    = tid >> 6;
    const int lane = tid & 63;
    const int ncol = lane & 15;   // MFMA n / A-row
    const int kg   = lane >> 4;   // k-group 0..3
    const int b0   = blockIdx.x * BBn;

    for (int i = tid; i < 16 * 264;    i += 512) ((__bf16*)in_bf)[i] = (__bf16)0.f;
    for (int i = tid; i < 2 * 16 * 72; i += 512) ((__bf16*)d_bf)[i]  = (__bf16)0.f;

    // ---- register-resident bf16 weight B-fragments ----
    // B[k][n]: lane holds k = kc*32 + kg*8 + e, n = col; W[col][k] row-major
    bf16x8 wih[3][8], whh[3][4], wdhf[2];
    float bih_r[3], bhh_r[3];
    #pragma unroll
    for (int nt = 0; nt < 3; ++nt) {
        const int c = nt * Hn + w * 16 + ncol;
        bih_r[nt] = b_ih[c];
        bhh_r[nt] = b_hh[c];
        #pragma unroll
        for (int kc = 0; kc < 8; ++kc) {
            const float* p = w_ih + (size_t)c * INn + kc * 32 + kg * 8;
            bf16x8 v;
            #pragma unroll
            for (int e = 0; e < 8; ++e) v[e] = (__bf16)p[e];
            wih[nt][kc] = v;
        }
        #pragma unroll
        for (int kc = 0; kc < 4; ++kc) {
            const float* p = w_hh + (size_t)c * Hn + kc * 32 + kg * 8;
            bf16x8 v;
            #pragma unroll
            for (int e = 0; e < 8; ++e) v[e] = (__bf16)p[e];
            whh[nt][kc] = v;
        }
    }
    const int ch = w * 16 + ncol;       // this lane's h/gamma column
    const float bdh_r = bdh[ch];
    #pragma unroll
    for (int kc = 0; kc < 2; ++kc) {
        const float* p = Wdh + (size_t)ch * Fn + kc * 32 + kg * 8;
        bf16x8 v;
        #pragma unroll
        for (int e = 0; e < 8; ++e) v[e] = (__bf16)p[e];
        wdhf[kc] = v;
    }

    // ---- input-streaming constants (thread = (row w, feature lane)) ----
    const int r_ld = w, f_ld = lane;
    const float wdxd_r = Wdx[(size_t)f_ld * Fn + f_ld];
    const float bdx_r  = bdx[f_ld];
    const float emp_r  = emp_mean[f_ld];
    const float* vp = values + (size_t)(b0 + r_ld) * Tn * Fn + f_ld;
    const float* mp = masks  + (size_t)(b0 + r_ld) * Tn * Fn + f_ld;
    const float* dp = deltas + (size_t)(b0 + r_ld) * Tn * Fn + f_ld;
    const float* lp = x_locf + (size_t)(b0 + r_ld) * Tn * Fn + f_ld;

    float h_reg[4] = {0.f, 0.f, 0.f, 0.f};   // h[kg*4+i][ch], valid on kg<2

    float x_c = vp[0], m_c = mp[0], d_c = dp[0], xl_c = lp[0];
    d_bf[0][r_ld][f_ld] = (__bf16)d_c;
    __syncthreads();

    const f32x4 fz = {0.f, 0.f, 0.f, 0.f};

    for (int t = 0; t < Tn; ++t) {
        const int cur = t & 1;

        // ---- Phase A: gamma_h MFMA + h decay (regs) + input prep + prefetch ----
        bf16x8 a0 = *(const bf16x8*)&d_bf[cur][ncol][kg * 8];
        bf16x8 a1 = *(const bf16x8*)&d_bf[cur][ncol][32 + kg * 8];
        f32x4 acc = fz;
        acc = __builtin_amdgcn_mfma_f32_16x16x32_bf16(a0, wdhf[0], acc, 0, 0, 0);
        acc = __builtin_amdgcn_mfma_f32_16x16x32_bf16(a1, wdhf[1], acc, 0, 0, 0);
        if (kg < 2) {
            #pragma unroll
            for (int i = 0; i < 4; ++i) {
                float g  = __expf(-fmaxf(acc[i] + bdh_r, 0.f));
                float hv = h_reg[i] * g;
                h_reg[i] = hv;
                in_bf[kg * 4 + i][Fn + ch] = (__bf16)hv;   // h at cols 64..191
            }
        }
        {
            float gx = __expf(-fmaxf(d_c * wdxd_r + bdx_r, 0.f));
            float xh = gx * xl_c + (1.f - gx) * emp_r;
            float xr = m_c * x_c + (1.f - m_c) * xh;
            in_bf[r_ld][f_ld]            = (__bf16)xr;
            in_bf[r_ld][Fn + Hn + f_ld]  = (__bf16)m_c;    // m at cols 192..255
        }
        const int off = (t + 1 < Tn) ? (t + 1) * Fn : t * Fn;
        float x_n = vp[off], m_n = mp[off], d_n = dp[off], xl_n = lp[off];
        __syncthreads();

        // ---- Phase B: gi/gh MFMAs + fused gates + h update (regs) ----
        bf16x8 af[8];
        #pragma unroll
        for (int kc = 0; kc < 8; ++kc)
            af[kc] = *(const bf16x8*)&in_bf[ncol][kc * 32 + kg * 8];
        f32x4 gacc[3], hacc[3];
        #pragma unroll
        for (int nt = 0; nt < 3; ++nt) { gacc[nt] = fz; hacc[nt] = fz; }
        #pragma unroll
        for (int kc = 0; kc < 8; ++kc)
            #pragma unroll
            for (int nt = 0; nt < 3; ++nt)
                gacc[nt] = __builtin_amdgcn_mfma_f32_16x16x32_bf16(af[kc], wih[nt][kc], gacc[nt], 0, 0, 0);
        #pragma unroll
        for (int kc = 0; kc < 4; ++kc)       // h occupies k 64..191 -> af[2..5]
            #pragma unroll
            for (int nt = 0; nt < 3; ++nt)
                hacc[nt] = __builtin_amdgcn_mfma_f32_16x16x32_bf16(af[kc + 2], whh[nt][kc], hacc[nt], 0, 0, 0);
        if (kg < 2) {
            #pragma unroll
            for (int i = 0; i < 4; ++i) {
                float rg = sigm(gacc[0][i] + bih_r[0] + hacc[0][i] + bhh_r[0]);
                float zg = sigm(gacc[1][i] + bih_r[1] + hacc[1][i] + bhh_r[1]);
                float hn = hacc[2][i] + bhh_r[2];
                float ng = tanh_(gacc[2][i] + bih_r[2] + rg * hn);
                h_reg[i] = (1.f - zg) * ng + zg * h_reg[i];
            }
        }
        // rotate prefetch regs; publish d for step t+1 into the other buffer
        x_c = x_n; m_c = m_n; d_c = d_n; xl_c = xl_n;
        d_bf[cur ^ 1][r_ld][f_ld] = (__bf16)d_n;
        __syncthreads();
    }

    // ---- epilogue: logits = h @ Wc^T + bc ; sigmoid ----
    if (kg < 2) {
        #pragma unroll
        for (int i = 0; i < 4; ++i) h_fin[kg * 4 + i][ch] = h_reg[i];
    }
    __syncthreads();
    if (tid < BBn) {
        float acc = bc[0];
        #pragma unroll 8
        for (int j = 0; j < Hn; ++j) acc += h_fin[tid][j] * Wc[j];
        out[b0 + tid] = sigm(acc);
    }
}

extern "C" void kernel_launch(void* const* d_in, const int* in_sizes, int n_in,
                              void* d_out, int out_size, void* d_ws, size_t ws_size,
                              hipStream_t stream)
{
    (void)in_sizes; (void)n_in; (void)out_size; (void)d_ws; (void)ws_size;
    grud_scan<<<dim3(Bsz / BBn), dim3(512), 0, stream>>>(
        (const float*)d_in[0],  (const float*)d_in[1],  (const float*)d_in[2],
        (const float*)d_in[3],  (const float*)d_in[4],  (const float*)d_in[5],
        (const float*)d_in[6],  (const float*)d_in[7],  (const float*)d_in[8],
        (const float*)d_in[9],  (const float*)d_in[10], (const float*)d_in[11],
        (const float*)d_in[12], (const float*)d_in[13], (const float*)d_in[14],
        (float*)d_out);
}

// Round 3
// 573.960 us; speedup vs baseline: 1.1812x; 1.0829x over previous
//
#include <hip/hip_runtime.h>
#include <hip/hip_bf16.h>

#define Bsz 2048
#define Tn  200
#define Fn  64
#define Hn  128
#define INn 256   // 2F + H
#define BBn 8     // batch rows per block

typedef __bf16 bf16x8 __attribute__((ext_vector_type(8)));
typedef float  f32x4  __attribute__((ext_vector_type(4)));

__device__ __forceinline__ float sigm(float x)  { return 1.f / (1.f + __expf(-x)); }
__device__ __forceinline__ float tanh_(float x) { return 1.f - 2.f / (__expf(2.f * x) + 1.f); }

// One block = 8 batch rows, 8 waves, scans all Tn steps with ONE relaxed
// barrier per step. Key identities:
//  - r,z gates: i_r+h_r = [x|h|m] @ (Wih_rz with Whh_rz folded into its
//    h-columns)^T  -> hacc[0..1] MFMAs eliminated (38 -> 30 MFMA/wave/step).
//  - gamma_h(t+1) depends only on d(t+1), not h -> compute its MFMA in the
//    post-barrier region of step t, apply in-register at step t+1 (no
//    separate phase, no extra barrier).
// Barrier = s_waitcnt lgkmcnt(0) + raw s_barrier: LDS writes are made
// visible but global prefetch loads stay in flight across the barrier.
__global__ __launch_bounds__(512, 2) void grud_scan(
    const float* __restrict__ values, const float* __restrict__ masks,
    const float* __restrict__ deltas, const float* __restrict__ x_locf,
    const float* __restrict__ emp_mean,
    const float* __restrict__ Wdh, const float* __restrict__ bdh,
    const float* __restrict__ Wdx, const float* __restrict__ bdx,
    const float* __restrict__ w_ih, const float* __restrict__ w_hh,
    const float* __restrict__ b_ih, const float* __restrict__ b_hh,
    const float* __restrict__ Wc, const float* __restrict__ bc,
    float* __restrict__ out)
{
    // double-buffered; row stride 264 bf16 (132 words) keeps b128 reads even
    __shared__ __align__(16) __bf16 in_bf[2][16][264];  // [x_rep | h | m], rows 8..15 zero
    __shared__ __align__(16) __bf16 d_bf[2][16][72];    // deltas (A for gamma MFMA)
    __shared__ float h_fin[BBn][Hn];                    // epilogue only

    const int tid  = threadIdx.x;
    const int w    = tid >> 6;
    const int lane = tid & 63;
    const int ncol = lane & 15;   // MFMA n / A-row
    const int kg   = lane >> 4;   // k-group 0..3
    const int b0   = blockIdx.x * BBn;

    for (int i = tid; i < 2 * 16 * 264; i += 512) ((__bf16*)in_bf)[i] = (__bf16)0.f;
    for (int i = tid; i < 2 * 16 * 72;  i += 512) ((__bf16*)d_bf)[i]  = (__bf16)0.f;

    // ---- register-resident bf16 weight B-fragments ----
    // B[k][n]: lane holds k = kc*32 + kg*8 + e, n = col; W[col][k] row-major.
    // For nt<2 (r,z) the h-columns (kc 2..5) get Whh_rz folded in.
    bf16x8 wih[3][8], whn[4], wdhf[2];
    float bih_r[3], bhh_r[3];
    #pragma unroll
    for (int nt = 0; nt < 3; ++nt) {
        const int c = nt * Hn + w * 16 + ncol;
        bih_r[nt] = b_ih[c];
        bhh_r[nt] = b_hh[c];
        #pragma unroll
        for (int kc = 0; kc < 8; ++kc) {
            const float* p = w_ih + (size_t)c * INn + kc * 32 + kg * 8;
            const bool fold = (nt < 2) & (kc >= 2) & (kc < 6);
            const float* q = w_hh + (size_t)c * Hn + (kc - 2) * 32 + kg * 8;
            bf16x8 v;
            #pragma unroll
            for (int e = 0; e < 8; ++e) v[e] = (__bf16)(p[e] + (fold ? q[e] : 0.f));
            wih[nt][kc] = v;
        }
    }
    {
        const int cn = 2 * Hn + w * 16 + ncol;   // n-gate columns of w_hh
        #pragma unroll
        for (int kc = 0; kc < 4; ++kc) {
            const float* q = w_hh + (size_t)cn * Hn + kc * 32 + kg * 8;
            bf16x8 v;
            #pragma unroll
            for (int e = 0; e < 8; ++e) v[e] = (__bf16)q[e];
            whn[kc] = v;
        }
    }
    const int ch = w * 16 + ncol;       // this lane's h/gamma column
    const float bdh_r = bdh[ch];
    #pragma unroll
    for (int kc = 0; kc < 2; ++kc) {
        const float* p = Wdh + (size_t)ch * Fn + kc * 32 + kg * 8;
        bf16x8 v;
        #pragma unroll
        for (int e = 0; e < 8; ++e) v[e] = (__bf16)p[e];
        wdhf[kc] = v;
    }
    const float bs0 = bih_r[0] + bhh_r[0];
    const float bs1 = bih_r[1] + bhh_r[1];

    // ---- input-streaming constants (thread = (row w, feature lane)) ----
    const int r_ld = w, f_ld = lane;
    const float wdxd_r = Wdx[(size_t)f_ld * Fn + f_ld];
    const float bdx_r  = bdx[f_ld];
    const float emp_r  = emp_mean[f_ld];
    const float* vp = values + (size_t)(b0 + r_ld) * Tn * Fn + f_ld;
    const float* mp = masks  + (size_t)(b0 + r_ld) * Tn * Fn + f_ld;
    const float* dp = deltas + (size_t)(b0 + r_ld) * Tn * Fn + f_ld;
    const float* lp = x_locf + (size_t)(b0 + r_ld) * Tn * Fn + f_ld;

    float h_reg[4] = {0.f, 0.f, 0.f, 0.f};   // h[kg*4+i][ch], valid on kg<2
    const f32x4 fz = {0.f, 0.f, 0.f, 0.f};

    // ---- prologue: prime t=0 ----
    float x_c = vp[0], m_c = mp[0], xl_c = lp[0];
    float d_cur = dp[0];          // d(t)   -> gamma_x at step t
    float d_w   = dp[Fn];         // d(t+1) -> written to LDS at step t
    d_bf[1][r_ld][f_ld] = (__bf16)d_cur;
    __syncthreads();
    f32x4 gam = fz;               // gamma-acc for step t (from d(t))
    {
        bf16x8 g0 = *(const bf16x8*)&d_bf[1][ncol][kg * 8];
        bf16x8 g1 = *(const bf16x8*)&d_bf[1][ncol][32 + kg * 8];
        gam = __builtin_amdgcn_mfma_f32_16x16x32_bf16(g0, wdhf[0], gam, 0, 0, 0);
        gam = __builtin_amdgcn_mfma_f32_16x16x32_bf16(g1, wdhf[1], gam, 0, 0, 0);
    }

    for (int t = 0; t < Tn; ++t) {
        const int buf = t & 1;

        // issue prefetch for t+1 (x,m,xl) and t+2 (d); lands next iteration
        const int o1 = (t + 1 < Tn ? t + 1 : Tn - 1) * Fn;
        const int o2 = (t + 2 < Tn ? t + 2 : Tn - 1) * Fn;
        const float x_n = vp[o1], m_n = mp[o1], xl_n = lp[o1], d_nn = dp[o2];

        // gamma_h(t) apply + publish decayed h (bf16) for the MFMAs
        if (kg < 2) {
            #pragma unroll
            for (int i = 0; i < 4; ++i) {
                float g = __expf(-fmaxf(gam[i] + bdh_r, 0.f));
                h_reg[i] *= g;
                in_bf[buf][kg * 4 + i][Fn + ch] = (__bf16)h_reg[i];
            }
        }
        // input prep for step t; stage d(t+1) for next step's gamma MFMA
        {
            float gx = __expf(-fmaxf(d_cur * wdxd_r + bdx_r, 0.f));
            float xh = gx * xl_c + (1.f - gx) * emp_r;
            float xr = m_c * x_c + (1.f - m_c) * xh;
            in_bf[buf][r_ld][f_ld]           = (__bf16)xr;
            in_bf[buf][r_ld][Fn + Hn + f_ld] = (__bf16)m_c;
            d_bf[buf][r_ld][f_ld]            = (__bf16)d_w;
        }
        // relaxed barrier: drain LDS only; global loads stay in flight
        asm volatile("s_waitcnt lgkmcnt(0)" ::: "memory");
        __builtin_amdgcn_s_barrier();

        // gamma-acc(t+1) (independent of h — runs alongside gate MFMAs)
        f32x4 gnew = fz;
        {
            bf16x8 g0 = *(const bf16x8*)&d_bf[buf][ncol][kg * 8];
            bf16x8 g1 = *(const bf16x8*)&d_bf[buf][ncol][32 + kg * 8];
            gnew = __builtin_amdgcn_mfma_f32_16x16x32_bf16(g0, wdhf[0], gnew, 0, 0, 0);
            gnew = __builtin_amdgcn_mfma_f32_16x16x32_bf16(g1, wdhf[1], gnew, 0, 0, 0);
        }

        // main MFMAs: gacc = [x_rep|h|m] @ (Wih+fold)^T ; nacc = h @ Whh_n^T
        bf16x8 af[8];
        #pragma unroll
        for (int kc = 0; kc < 8; ++kc)
            af[kc] = *(const bf16x8*)&in_bf[buf][ncol][kc * 32 + kg * 8];
        f32x4 gacc[3] = {fz, fz, fz}, nacc = fz;
        #pragma unroll
        for (int kc = 0; kc < 8; ++kc)
            #pragma unroll
            for (int nt = 0; nt < 3; ++nt)
                gacc[nt] = __builtin_amdgcn_mfma_f32_16x16x32_bf16(af[kc], wih[nt][kc], gacc[nt], 0, 0, 0);
        #pragma unroll
        for (int kc = 0; kc < 4; ++kc)       // h occupies k 64..191 -> af[2..5]
            nacc = __builtin_amdgcn_mfma_f32_16x16x32_bf16(af[kc + 2], whn[kc], nacc, 0, 0, 0);

        // gates + h update (register-local)
        if (kg < 2) {
            #pragma unroll
            for (int i = 0; i < 4; ++i) {
                float rg = sigm(gacc[0][i] + bs0);
                float zg = sigm(gacc[1][i] + bs1);
                float hn = nacc[i] + bhh_r[2];
                float ng = tanh_(gacc[2][i] + bih_r[2] + rg * hn);
                h_reg[i] = (1.f - zg) * ng + zg * h_reg[i];
            }
        }
        // rotate pipeline registers
        gam = gnew;
        x_c = x_n; m_c = m_n; xl_c = xl_n;
        d_cur = d_w; d_w = d_nn;
    }

    // ---- epilogue: logits = h @ Wc^T + bc ; sigmoid ----
    if (kg < 2) {
        #pragma unroll
        for (int i = 0; i < 4; ++i) h_fin[kg * 4 + i][ch] = h_reg[i];
    }
    __syncthreads();
    if (tid < BBn) {
        float acc = bc[0];
        #pragma unroll 8
        for (int j = 0; j < Hn; ++j) acc += h_fin[tid][j] * Wc[j];
        out[b0 + tid] = sigm(acc);
    }
}

extern "C" void kernel_launch(void* const* d_in, const int* in_sizes, int n_in,
                              void* d_out, int out_size, void* d_ws, size_t ws_size,
                              hipStream_t stream)
{
    (void)in_sizes; (void)n_in; (void)out_size; (void)d_ws; (void)ws_size;
    grud_scan<<<dim3(Bsz / BBn), dim3(512), 0, stream>>>(
        (const float*)d_in[0],  (const float*)d_in[1],  (const float*)d_in[2],
        (const float*)d_in[3],  (const float*)d_in[4],  (const float*)d_in[5],
        (const float*)d_in[6],  (const float*)d_in[7],  (const float*)d_in[8],
        (const float*)d_in[9],  (const float*)d_in[10], (const float*)d_in[11],
        (const float*)d_in[12], (const float*)d_in[13], (const float*)d_in[14],
        (float*)d_out);
}